// Round 2
// baseline (1301.520 us; speedup 1.0000x reference)
//
#include <hip/hip_runtime.h>

typedef __attribute__((ext_vector_type(8))) short short8;
typedef __attribute__((ext_vector_type(4))) float floatx4;

#define MFMA(a, b, c) __builtin_amdgcn_mfma_f32_16x16x32_bf16((a), (b), (c), 0, 0, 0)

constexpr int N_NODES = 50000;
constexpr int N_EDGES = 800000;
constexpr int XS_STRIDE = 264;  // bf16 units; 528B row = 132 dw, %32=4 -> <=2-way bank alias (free)
constexpr int MS_STRIDE = 132;  // fp32 units; same byte stride, Ms overlays Xs
constexpr int YS_STRIDE = 136;
constexpr int EDGE_TILES = N_EDGES / 64;         // 12500 exact
constexpr int NODE_TILES = (N_NODES + 63) / 64;  // 782

__device__ __forceinline__ unsigned short f2b(float x) {
  union { float f; unsigned u; } c; c.f = x;
  unsigned r = c.u + 0x7FFFu + ((c.u >> 16) & 1u);
  return (unsigned short)(r >> 16);
}

// ---- weight prep: fp32 [K][N] -> bf16 [N][K] ----
__global__ void prep_weights(const float* __restrict__ W1a, const float* __restrict__ W1b,
                             const float* __restrict__ W2a, const float* __restrict__ W2b,
                             unsigned short* __restrict__ wbuf) {
  unsigned short* W1aT = wbuf;
  unsigned short* W1bT = wbuf + 32768;
  unsigned short* W2aT = wbuf + 49152;
  unsigned short* W2bT = wbuf + 65536;
  const int t = blockIdx.x * blockDim.x + threadIdx.x;
  const int stride = gridDim.x * blockDim.x;
  for (int i = t; i < 128 * 256; i += stride) {
    const int n = i >> 8, k = i & 255;
    W1aT[i] = f2b(W1a[k * 128 + n]);
  }
  for (int i = t; i < 128 * 128; i += stride) {
    const int n = i >> 7, k = i & 127;
    W1bT[i] = f2b(W1b[k * 128 + n]);
    W2aT[i] = f2b(W2a[k * 128 + n]);
    W2bT[i] = f2b(W2b[k * 128 + n]);
  }
}

// ---- counting sort by dst: histogram (+ zero agg), scan, scatter ----
__global__ void hist_and_zero(const int* __restrict__ dst, int* __restrict__ hist,
                              float4* __restrict__ agg4) {
  const int t = blockIdx.x * blockDim.x + threadIdx.x;
  const int stride = gridDim.x * blockDim.x;
  const float4 z = {0.f, 0.f, 0.f, 0.f};
  for (int i = t; i < N_NODES * 32; i += stride) agg4[i] = z;
  for (int e = t; e < N_EDGES; e += stride) atomicAdd(&hist[dst[e]], 1);
}

__global__ void scan_hist(const int* __restrict__ hist, int* __restrict__ cursor) {
  __shared__ int part[1024];
  const int t = threadIdx.x;
  constexpr int CH = (N_NODES + 1023) / 1024;  // 49
  const int base = t * CH;
  int s = 0;
  for (int i = 0; i < CH; ++i) {
    const int idx = base + i;
    if (idx < N_NODES) s += hist[idx];
  }
  part[t] = s;
  __syncthreads();
  for (int off = 1; off < 1024; off <<= 1) {
    const int v = part[t];
    const int add = (t >= off) ? part[t - off] : 0;
    __syncthreads();
    part[t] = v + add;
    __syncthreads();
  }
  int ex = (t == 0) ? 0 : part[t - 1];
  for (int i = 0; i < CH; ++i) {
    const int idx = base + i;
    if (idx < N_NODES) {
      cursor[idx] = ex;
      ex += hist[idx];
    }
  }
}

__global__ void scatter_perm(const int* __restrict__ dst, int* __restrict__ cursor,
                             int* __restrict__ perm) {
  const int e = blockIdx.x * 256 + threadIdx.x;
  if (e < N_EDGES) {
    const int p = atomicAdd(&cursor[dst[e]], 1);
    perm[p] = e;
  }
}

// ---- edge MLP on dst-sorted edges + in-tile segmented reduction ----
__global__ __launch_bounds__(256, 3) void edge_mlp_sorted(
    const float* __restrict__ nf, const float* __restrict__ ef,
    const int* __restrict__ src, const int* __restrict__ dst,
    const int* __restrict__ perm,
    const float* __restrict__ b1a, const float* __restrict__ b1b,
    const unsigned short* __restrict__ W1aT, const unsigned short* __restrict__ W1bT,
    float* __restrict__ agg) {
  __shared__ __align__(16) unsigned short Xs[64 * XS_STRIDE];  // also Ms (fp32) after GEMM2
  __shared__ __align__(16) unsigned short Ys[64 * YS_STRIDE];
  __shared__ int srcS[64];
  __shared__ int dstS[64];
  float* const Ms = (float*)Xs;

  const int tid = threadIdx.x;
  const int wave = tid >> 6;
  const int lane = tid & 63;
  const int l16 = lane & 15;
  const int quad = lane >> 4;
  const int nbase = wave * 32;

  short8 bfr1[2][8];
  short8 bfr2[2][4];
  float bias1[2], bias2[2];
#pragma unroll
  for (int t = 0; t < 2; ++t) {
    const int n = nbase + t * 16 + l16;
#pragma unroll
    for (int ks = 0; ks < 8; ++ks)
      bfr1[t][ks] = *(const short8*)(W1aT + n * 256 + ks * 32 + quad * 8);
#pragma unroll
    for (int ks = 0; ks < 4; ++ks)
      bfr2[t][ks] = *(const short8*)(W1bT + n * 128 + ks * 32 + quad * 8);
    bias1[t] = b1a[n];
    bias2[t] = b1b[n];
  }
  __shared__ int eS[64];

  for (int tile = blockIdx.x; tile < EDGE_TILES; tile += gridDim.x) {
    const int ebase = tile * 64;
    __syncthreads();  // protect Ms/dstS/eS from previous iteration readers
    if (tid < 64) {
      const int e = perm[ebase + tid];
      eS[tid] = e;
      srcS[tid] = src[e];
      dstS[tid] = dst[e];
    }
    __syncthreads();

    // stage X = [nf[src] | ef] as bf16
#pragma unroll
    for (int i = 0; i < 16; ++i) {
      const int fidx = tid + 256 * i;
      const int r = fidx >> 6;
      const int c4 = fidx & 63;
      float4 v;
      if (c4 < 32) {
        v = ((const float4*)nf)[(long)srcS[r] * 32 + c4];
      } else {
        v = ((const float4*)ef)[(long)eS[r] * 32 + (c4 - 32)];
      }
      unsigned short* p = &Xs[r * XS_STRIDE + c4 * 4];
      p[0] = f2b(v.x); p[1] = f2b(v.y); p[2] = f2b(v.z); p[3] = f2b(v.w);
    }
    __syncthreads();

    // GEMM1: Y1 = relu(X @ W1a + b1a)
    floatx4 acc[4][2];
#pragma unroll
    for (int mt = 0; mt < 4; ++mt)
#pragma unroll
      for (int t = 0; t < 2; ++t)
        acc[mt][t] = (floatx4){bias1[t], bias1[t], bias1[t], bias1[t]};
#pragma unroll
    for (int ks = 0; ks < 8; ++ks)
#pragma unroll
      for (int mt = 0; mt < 4; ++mt) {
        const short8 a = *(const short8*)(&Xs[(mt * 16 + l16) * XS_STRIDE + ks * 32 + quad * 8]);
        acc[mt][0] = MFMA(a, bfr1[0][ks], acc[mt][0]);
        acc[mt][1] = MFMA(a, bfr1[1][ks], acc[mt][1]);
      }
#pragma unroll
    for (int mt = 0; mt < 4; ++mt)
#pragma unroll
      for (int t = 0; t < 2; ++t)
#pragma unroll
        for (int r = 0; r < 4; ++r) {
          const int row = mt * 16 + quad * 4 + r;
          const int col = nbase + t * 16 + l16;
          Ys[row * YS_STRIDE + col] = f2b(fmaxf(acc[mt][t][r], 0.f));
        }
    __syncthreads();  // Ys ready; also: all GEMM1 Xs reads done -> Ms may overlay Xs

    // GEMM2: M = Y1 @ W1b + b1b -> Ms (fp32, overlays Xs)
    floatx4 acc2[4][2];
#pragma unroll
    for (int mt = 0; mt < 4; ++mt)
#pragma unroll
      for (int t = 0; t < 2; ++t)
        acc2[mt][t] = (floatx4){bias2[t], bias2[t], bias2[t], bias2[t]};
#pragma unroll
    for (int ks = 0; ks < 4; ++ks)
#pragma unroll
      for (int mt = 0; mt < 4; ++mt) {
        const short8 a = *(const short8*)(&Ys[(mt * 16 + l16) * YS_STRIDE + ks * 32 + quad * 8]);
        acc2[mt][0] = MFMA(a, bfr2[0][ks], acc2[mt][0]);
        acc2[mt][1] = MFMA(a, bfr2[1][ks], acc2[mt][1]);
      }
#pragma unroll
    for (int mt = 0; mt < 4; ++mt)
#pragma unroll
      for (int t = 0; t < 2; ++t)
#pragma unroll
        for (int r = 0; r < 4; ++r) {
          const int row = mt * 16 + quad * 4 + r;
          const int col = nbase + t * 16 + l16;
          Ms[row * MS_STRIDE + col] = acc2[mt][t][r];
        }
    __syncthreads();  // Ms ready

    // segmented reduction over sorted dst; interior segments are plain stores
    if (tid < 128) {
      const int c = tid;
      float a = 0.f;
      int sstart = 0;
      for (int r = 0; r < 64; ++r) {
        a += Ms[r * MS_STRIDE + c];
        const bool endseg = (r == 63) || (dstS[r + 1] != dstS[r]);
        if (endseg) {
          float* p = &agg[(long)dstS[r] * 128 + c];
          if (sstart > 0 && r < 63) {
            *p = a;  // segment fully inside tile: exclusive owner
          } else {
            unsafeAtomicAdd(p, a);  // may span tile boundary
          }
          a = 0.f;
          sstart = r + 1;
        }
      }
    }
  }
}

// ---- node MLP: out = relu((agg + nf) @ W2a + b2a) @ W2b + b2b ----
__global__ __launch_bounds__(256) void node_mlp(
    const float* __restrict__ nf, const float* __restrict__ agg,
    const float* __restrict__ b2a, const float* __restrict__ b2b,
    const unsigned short* __restrict__ W2aT, const unsigned short* __restrict__ W2bT,
    float* __restrict__ out) {
  __shared__ __align__(16) unsigned short Xs[64 * YS_STRIDE];
  __shared__ __align__(16) unsigned short Ys[64 * YS_STRIDE];

  const int tid = threadIdx.x;
  const int wave = tid >> 6;
  const int lane = tid & 63;
  const int l16 = lane & 15;
  const int quad = lane >> 4;
  const int nbase = wave * 32;
  const int rbase = blockIdx.x * 64;

  short8 bfrA[2][4], bfrB[2][4];
  float biasA[2], biasB[2];
#pragma unroll
  for (int t = 0; t < 2; ++t) {
    const int n = nbase + t * 16 + l16;
#pragma unroll
    for (int ks = 0; ks < 4; ++ks) {
      bfrA[t][ks] = *(const short8*)(W2aT + n * 128 + ks * 32 + quad * 8);
      bfrB[t][ks] = *(const short8*)(W2bT + n * 128 + ks * 32 + quad * 8);
    }
    biasA[t] = b2a[n];
    biasB[t] = b2b[n];
  }

#pragma unroll
  for (int i = 0; i < 8; ++i) {
    const int fidx = tid + 256 * i;
    const int r = fidx >> 5;
    const int c4 = fidx & 31;
    const long gr = min(rbase + r, N_NODES - 1);
    const float4 a = ((const float4*)agg)[gr * 32 + c4];
    const float4 n = ((const float4*)nf)[gr * 32 + c4];
    unsigned short* p = &Xs[r * YS_STRIDE + c4 * 4];
    p[0] = f2b(a.x + n.x); p[1] = f2b(a.y + n.y);
    p[2] = f2b(a.z + n.z); p[3] = f2b(a.w + n.w);
  }
  __syncthreads();

  floatx4 acc[4][2];
#pragma unroll
  for (int mt = 0; mt < 4; ++mt)
#pragma unroll
    for (int t = 0; t < 2; ++t)
      acc[mt][t] = (floatx4){biasA[t], biasA[t], biasA[t], biasA[t]};
#pragma unroll
  for (int ks = 0; ks < 4; ++ks)
#pragma unroll
    for (int mt = 0; mt < 4; ++mt) {
      const short8 a = *(const short8*)(&Xs[(mt * 16 + l16) * YS_STRIDE + ks * 32 + quad * 8]);
      acc[mt][0] = MFMA(a, bfrA[0][ks], acc[mt][0]);
      acc[mt][1] = MFMA(a, bfrA[1][ks], acc[mt][1]);
    }
#pragma unroll
  for (int mt = 0; mt < 4; ++mt)
#pragma unroll
    for (int t = 0; t < 2; ++t)
#pragma unroll
      for (int r = 0; r < 4; ++r) {
        const int row = mt * 16 + quad * 4 + r;
        const int col = nbase + t * 16 + l16;
        Ys[row * YS_STRIDE + col] = f2b(fmaxf(acc[mt][t][r], 0.f));
      }
  __syncthreads();

  floatx4 acc2[4][2];
#pragma unroll
  for (int mt = 0; mt < 4; ++mt)
#pragma unroll
    for (int t = 0; t < 2; ++t)
      acc2[mt][t] = (floatx4){biasB[t], biasB[t], biasB[t], biasB[t]};
#pragma unroll
  for (int ks = 0; ks < 4; ++ks)
#pragma unroll
    for (int mt = 0; mt < 4; ++mt) {
      const short8 a = *(const short8*)(&Ys[(mt * 16 + l16) * YS_STRIDE + ks * 32 + quad * 8]);
      acc2[mt][0] = MFMA(a, bfrB[0][ks], acc2[mt][0]);
      acc2[mt][1] = MFMA(a, bfrB[1][ks], acc2[mt][1]);
    }
#pragma unroll
  for (int mt = 0; mt < 4; ++mt)
#pragma unroll
    for (int t = 0; t < 2; ++t)
#pragma unroll
      for (int r = 0; r < 4; ++r) {
        const int row = mt * 16 + quad * 4 + r;
        const int grow = rbase + row;
        if (grow < N_NODES) {
          const int col = nbase + t * 16 + l16;
          out[(long)grow * 128 + col] = acc2[mt][t][r];
        }
      }
}

extern "C" void kernel_launch(void* const* d_in, const int* in_sizes, int n_in,
                              void* d_out, int out_size, void* d_ws, size_t ws_size,
                              hipStream_t stream) {
  const float* nf = (const float*)d_in[0];
  const float* ef = (const float*)d_in[1];
  const int* src = (const int*)d_in[2];
  const int* dst = (const int*)d_in[3];
  const float* W1a = (const float*)d_in[4];
  const float* b1a = (const float*)d_in[5];
  const float* W1b = (const float*)d_in[6];
  const float* b1b = (const float*)d_in[7];
  const float* W2a = (const float*)d_in[8];
  const float* b2a = (const float*)d_in[9];
  const float* W2b = (const float*)d_in[10];
  const float* b2b = (const float*)d_in[11];
  float* out = (float*)d_out;

  // ws layout (all 16B-aligned):
  //   agg    fp32 [50000*128]        @ 0          (25,600,000 B)
  //   wbuf   bf16 weights            @ 25,600,000 (163,840 B)
  //   hist   int  [50000]            @ 25,763,840 (200,000 B)
  //   cursor int  [50000]            @ 25,963,840 (200,000 B)
  //   perm   int  [800000]           @ 26,163,840 (3,200,000 B) -> ends 29,363,840
  char* ws = (char*)d_ws;
  float* agg = (float*)ws;
  unsigned short* wbuf = (unsigned short*)(ws + 25600000);
  int* hist = (int*)(ws + 25763840);
  int* cursor = (int*)(ws + 25963840);
  int* perm = (int*)(ws + 26163840);
  const unsigned short* W1aT = wbuf;
  const unsigned short* W1bT = wbuf + 32768;
  const unsigned short* W2aT = wbuf + 49152;
  const unsigned short* W2bT = wbuf + 65536;

  hipMemsetAsync(hist, 0, N_NODES * sizeof(int), stream);
  prep_weights<<<64, 256, 0, stream>>>(W1a, W1b, W2a, W2b, wbuf);
  hist_and_zero<<<1024, 256, 0, stream>>>(dst, hist, (float4*)agg);
  scan_hist<<<1, 1024, 0, stream>>>(hist, cursor);
  scatter_perm<<<(N_EDGES + 255) / 256, 256, 0, stream>>>(dst, cursor, perm);
  edge_mlp_sorted<<<3072, 256, 0, stream>>>(nf, ef, src, dst, perm, b1a, b1b, W1aT, W1bT, agg);
  node_mlp<<<NODE_TILES, 256, 0, stream>>>(nf, agg, b2a, b2b, W2aT, W2bT, out);
}

// Round 3
// 1009.637 us; speedup vs baseline: 1.2891x; 1.2891x over previous
//
#include <hip/hip_runtime.h>
#include <hip/hip_bf16.h>

typedef __attribute__((ext_vector_type(8))) short short8;
typedef __attribute__((ext_vector_type(4))) float floatx4;
typedef unsigned short ushort_t;

#define MFMA(a, b, c) __builtin_amdgcn_mfma_f32_16x16x32_bf16((a), (b), (c), 0, 0, 0)

constexpr int N_NODES = 50000;
constexpr int N_EDGES = 800000;
constexpr int EDGE_BLOCKS = N_EDGES / 32;        // 25000 (exact)
constexpr int NODE_TILES = (N_NODES + 63) / 64;  // 782
constexpr int YS_STRIDE = 136;                   // u16; 272B row, 16B-aligned, ~2-way bank alias (free)

__device__ __forceinline__ unsigned short f2b(float x) {
  union { float f; unsigned u; } c; c.f = x;
  unsigned r = c.u + 0x7FFFu + ((c.u >> 16) & 1u);
  return (unsigned short)(r >> 16);
}

__device__ __forceinline__ unsigned pk2(float x, float y) {
  // packed RNE fp32->bf16 (v_cvt_pk_bf16_f32 on gfx950)
  __hip_bfloat162 h = __float22bfloat162_rn(float2{x, y});
  unsigned u; __builtin_memcpy(&u, &h, 4);
  return u;
}

__device__ __forceinline__ short8 mk_frag(const float4 a, const float4 b) {
  union { short8 s; unsigned u[4]; } r;
  r.u[0] = pk2(a.x, a.y); r.u[1] = pk2(a.z, a.w);
  r.u[2] = pk2(b.x, b.y); r.u[3] = pk2(b.z, b.w);
  return r.s;
}

// ---- prep: zero agg + build weights ----
// W1s1/W1s2: frag-swizzled [fragblock][lane][8k] so one wave B-load = contiguous 1KB.
// W2aT/W2bT: [n][k] row-major bf16 (node kernel preloads to registers once).
__global__ void prep(const float* __restrict__ W1a, const float* __restrict__ W1b,
                     const float* __restrict__ W2a, const float* __restrict__ W2b,
                     ushort_t* __restrict__ wbuf, float4* __restrict__ agg4) {
  const int t = blockIdx.x * blockDim.x + threadIdx.x;
  const int stride = gridDim.x * blockDim.x;
  const float4 z = {0.f, 0.f, 0.f, 0.f};
  for (int i = t; i < N_NODES * 32; i += stride) agg4[i] = z;

  ushort_t* W1s1 = wbuf;           // 32768: GEMM1 frags (ks=0..7, nt=0..7)
  ushort_t* W1s2 = wbuf + 32768;   // 16384: GEMM2 frags (ks=0..3, nt=0..7)
  ushort_t* W2aT = wbuf + 49152;   // 16384
  ushort_t* W2bT = wbuf + 65536;   // 16384

  for (int i = t; i < 32768; i += stride) {
    const int j = i & 7, lane = (i >> 3) & 63, fb = i >> 9;
    const int ks = fb >> 3, nt = fb & 7;
    const int k = ks * 32 + (lane >> 4) * 8 + j, n = nt * 16 + (lane & 15);
    W1s1[i] = f2b(W1a[k * 128 + n]);
  }
  for (int i = t; i < 16384; i += stride) {
    const int j = i & 7, lane = (i >> 3) & 63, fb = i >> 9;
    const int ks = fb >> 3, nt = fb & 7;
    const int k = ks * 32 + (lane >> 4) * 8 + j, n = nt * 16 + (lane & 15);
    W1s2[i] = f2b(W1b[k * 128 + n]);
  }
  for (int i = t; i < 16384; i += stride) {
    const int n = i >> 7, k = i & 127;
    W2aT[i] = f2b(W2a[k * 128 + n]);
    W2bT[i] = f2b(W2b[k * 128 + n]);
  }
}

// ---- edge MLP: 1 wave = one 32-edge tile, barrier-free ----
__global__ __launch_bounds__(64, 4) void edge_mlp(
    const float* __restrict__ nf, const float* __restrict__ ef,
    const int* __restrict__ src, const int* __restrict__ dst,
    const float* __restrict__ b1a, const float* __restrict__ b1b,
    const ushort_t* __restrict__ W1s1, const ushort_t* __restrict__ W1s2,
    float* __restrict__ agg) {
  __shared__ __align__(16) ushort_t Ys[32 * YS_STRIDE];  // wave-private (1 wave/block)

  const int lane = threadIdx.x;
  const int l16 = lane & 15;
  const int quad = lane >> 4;
  const int tb = blockIdx.x * 32;

  const int s0 = src[tb + l16];        // A row for mt=0
  const int s1 = src[tb + 16 + l16];   // A row for mt=1

  // GEMM1: acc[mt][nt] over K=256 (ks 0..3 = nf[src], 4..7 = ef)
  floatx4 acc[2][8];
#pragma unroll
  for (int nt = 0; nt < 8; ++nt) {
    const float bz = b1a[nt * 16 + l16];
    acc[0][nt] = (floatx4){bz, bz, bz, bz};
    acc[1][nt] = acc[0][nt];
  }
#pragma unroll
  for (int ks = 0; ks < 8; ++ks) {
    short8 a0, a1;
    if (ks < 4) {
      const float4* p0 = (const float4*)nf + (long)s0 * 32 + ks * 8 + quad * 2;
      const float4* p1 = (const float4*)nf + (long)s1 * 32 + ks * 8 + quad * 2;
      a0 = mk_frag(p0[0], p0[1]);
      a1 = mk_frag(p1[0], p1[1]);
    } else {
      const float4* p0 = (const float4*)ef + (long)(tb + l16) * 32 + (ks - 4) * 8 + quad * 2;
      const float4* p1 = (const float4*)ef + (long)(tb + 16 + l16) * 32 + (ks - 4) * 8 + quad * 2;
      a0 = mk_frag(p0[0], p0[1]);
      a1 = mk_frag(p1[0], p1[1]);
    }
#pragma unroll
    for (int nt = 0; nt < 8; ++nt) {
      const short8 b = *(const short8*)(W1s1 + ((ks * 8 + nt) * 64 + lane) * 8);
      acc[0][nt] = MFMA(a0, b, acc[0][nt]);
      acc[1][nt] = MFMA(a1, b, acc[1][nt]);
    }
  }

  // relu -> Ys (bf16, A-layout for GEMM2); within-wave: no barrier needed
#pragma unroll
  for (int mt = 0; mt < 2; ++mt)
#pragma unroll
    for (int nt = 0; nt < 8; ++nt)
#pragma unroll
      for (int r = 0; r < 4; ++r)
        Ys[(mt * 16 + quad * 4 + r) * YS_STRIDE + nt * 16 + l16] =
            f2b(fmaxf(acc[mt][nt][r], 0.f));

  // GEMM2: M = Y1 @ W1b + b1b
  floatx4 acc2[2][8];
#pragma unroll
  for (int nt = 0; nt < 8; ++nt) {
    const float bz = b1b[nt * 16 + l16];
    acc2[0][nt] = (floatx4){bz, bz, bz, bz};
    acc2[1][nt] = acc2[0][nt];
  }
#pragma unroll
  for (int ks = 0; ks < 4; ++ks) {
    const short8 a0 = *(const short8*)(&Ys[l16 * YS_STRIDE + ks * 32 + quad * 8]);
    const short8 a1 = *(const short8*)(&Ys[(16 + l16) * YS_STRIDE + ks * 32 + quad * 8]);
#pragma unroll
    for (int nt = 0; nt < 8; ++nt) {
      const short8 b = *(const short8*)(W1s2 + ((ks * 8 + nt) * 64 + lane) * 8);
      acc2[0][nt] = MFMA(a0, b, acc2[0][nt]);
      acc2[1][nt] = MFMA(a1, b, acc2[1][nt]);
    }
  }

  // scatter-add to agg (fire-and-forget; no barrier behind it)
#pragma unroll
  for (int mt = 0; mt < 2; ++mt)
#pragma unroll
    for (int r = 0; r < 4; ++r) {
      const int d = dst[tb + mt * 16 + quad * 4 + r];
      float* base = &agg[(long)d * 128 + l16];
#pragma unroll
      for (int nt = 0; nt < 8; ++nt)
        unsafeAtomicAdd(base + nt * 16, acc2[mt][nt][r]);
    }
}

// ---- node MLP: out = relu((agg + nf) @ W2a + b2a) @ W2b + b2b ----
__global__ __launch_bounds__(256) void node_mlp(
    const float* __restrict__ nf, const float* __restrict__ agg,
    const float* __restrict__ b2a, const float* __restrict__ b2b,
    const ushort_t* __restrict__ W2aT, const ushort_t* __restrict__ W2bT,
    float* __restrict__ out) {
  __shared__ __align__(16) ushort_t Xs[64 * YS_STRIDE];
  __shared__ __align__(16) ushort_t Ys2[64 * YS_STRIDE];

  const int tid = threadIdx.x;
  const int wave = tid >> 6;
  const int lane = tid & 63;
  const int l16 = lane & 15;
  const int quad = lane >> 4;
  const int nbase = wave * 32;
  const int rbase = blockIdx.x * 64;

  short8 bfrA[2][4], bfrB[2][4];
  float biasA[2], biasB[2];
#pragma unroll
  for (int t = 0; t < 2; ++t) {
    const int n = nbase + t * 16 + l16;
#pragma unroll
    for (int ks = 0; ks < 4; ++ks) {
      bfrA[t][ks] = *(const short8*)(W2aT + n * 128 + ks * 32 + quad * 8);
      bfrB[t][ks] = *(const short8*)(W2bT + n * 128 + ks * 32 + quad * 8);
    }
    biasA[t] = b2a[n];
    biasB[t] = b2b[n];
  }

#pragma unroll
  for (int i = 0; i < 8; ++i) {
    const int fidx = tid + 256 * i;
    const int r = fidx >> 5;
    const int c4 = fidx & 31;
    const long gr = min(rbase + r, N_NODES - 1);
    const float4 a = ((const float4*)agg)[gr * 32 + c4];
    const float4 n = ((const float4*)nf)[gr * 32 + c4];
    unsigned* p = (unsigned*)&Xs[r * YS_STRIDE + c4 * 4];
    p[0] = pk2(a.x + n.x, a.y + n.y);
    p[1] = pk2(a.z + n.z, a.w + n.w);
  }
  __syncthreads();

  floatx4 acc[4][2];
#pragma unroll
  for (int mt = 0; mt < 4; ++mt)
#pragma unroll
    for (int t = 0; t < 2; ++t)
      acc[mt][t] = (floatx4){biasA[t], biasA[t], biasA[t], biasA[t]};
#pragma unroll
  for (int ks = 0; ks < 4; ++ks)
#pragma unroll
    for (int mt = 0; mt < 4; ++mt) {
      const short8 a = *(const short8*)(&Xs[(mt * 16 + l16) * YS_STRIDE + ks * 32 + quad * 8]);
      acc[mt][0] = MFMA(a, bfrA[0][ks], acc[mt][0]);
      acc[mt][1] = MFMA(a, bfrA[1][ks], acc[mt][1]);
    }
#pragma unroll
  for (int mt = 0; mt < 4; ++mt)
#pragma unroll
    for (int t = 0; t < 2; ++t)
#pragma unroll
      for (int r = 0; r < 4; ++r) {
        const int row = mt * 16 + quad * 4 + r;
        const int col = nbase + t * 16 + l16;
        Ys2[row * YS_STRIDE + col] = f2b(fmaxf(acc[mt][t][r], 0.f));
      }
  __syncthreads();

  floatx4 acc2[4][2];
#pragma unroll
  for (int mt = 0; mt < 4; ++mt)
#pragma unroll
    for (int t = 0; t < 2; ++t)
      acc2[mt][t] = (floatx4){biasB[t], biasB[t], biasB[t], biasB[t]};
#pragma unroll
  for (int ks = 0; ks < 4; ++ks)
#pragma unroll
    for (int mt = 0; mt < 4; ++mt) {
      const short8 a = *(const short8*)(&Ys2[(mt * 16 + l16) * YS_STRIDE + ks * 32 + quad * 8]);
      acc2[mt][0] = MFMA(a, bfrB[0][ks], acc2[mt][0]);
      acc2[mt][1] = MFMA(a, bfrB[1][ks], acc2[mt][1]);
    }
#pragma unroll
  for (int mt = 0; mt < 4; ++mt)
#pragma unroll
    for (int t = 0; t < 2; ++t)
#pragma unroll
      for (int r = 0; r < 4; ++r) {
        const int row = mt * 16 + quad * 4 + r;
        const int grow = rbase + row;
        if (grow < N_NODES) {
          const int col = nbase + t * 16 + l16;
          out[(long)grow * 128 + col] = acc2[mt][t][r];
        }
      }
}

extern "C" void kernel_launch(void* const* d_in, const int* in_sizes, int n_in,
                              void* d_out, int out_size, void* d_ws, size_t ws_size,
                              hipStream_t stream) {
  const float* nf = (const float*)d_in[0];
  const float* ef = (const float*)d_in[1];
  const int* src = (const int*)d_in[2];
  const int* dst = (const int*)d_in[3];
  const float* W1a = (const float*)d_in[4];
  const float* b1a = (const float*)d_in[5];
  const float* W1b = (const float*)d_in[6];
  const float* b1b = (const float*)d_in[7];
  const float* W2a = (const float*)d_in[8];
  const float* b2a = (const float*)d_in[9];
  const float* W2b = (const float*)d_in[10];
  const float* b2b = (const float*)d_in[11];
  float* out = (float*)d_out;

  // ws: agg fp32 [50000*128] @0 (25.6MB), wbuf bf16 weights @25600000 (163840B)
  char* ws = (char*)d_ws;
  float* agg = (float*)ws;
  ushort_t* wbuf = (ushort_t*)(ws + 25600000);
  const ushort_t* W1s1 = wbuf;
  const ushort_t* W1s2 = wbuf + 32768;
  const ushort_t* W2aT = wbuf + 49152;
  const ushort_t* W2bT = wbuf + 65536;

  prep<<<1024, 256, 0, stream>>>(W1a, W1b, W2a, W2b, wbuf, (float4*)agg);
  edge_mlp<<<EDGE_BLOCKS, 64, 0, stream>>>(nf, ef, src, dst, b1a, b1b, W1s1, W1s2, agg);
  node_mlp<<<NODE_TILES, 256, 0, stream>>>(nf, agg, b2a, b2b, W2aT, W2bT, out);
}